// Round 5
// baseline (245.352 us; speedup 1.0000x reference)
//
#include <hip/hip_runtime.h>
#include <math.h>

#define E_N 40000
#define D_N 200
#define L_N 100
#define K_N 300
#define B_N 32

typedef float  f32x4 __attribute__((ext_vector_type(4)));
typedef short  s16x8 __attribute__((ext_vector_type(8)));

// ws layout (f32 units):
//  sh  [100][32] @ 0      r_l*(num_lit[e1_b,l]-c_l)
//  w   [100][32] @ 3200   nf_w[rel_b,l]
//  nr  [100]     @ 6400   -r_l,  r_l = sqrt(log2e/var_l)
//  s0  [32]      @ 6500   q[b,:].b_lit   (pad to 6532)
//  pA  u16[2][10][64][8] @ 6532   p in MFMA A-frag layout, bf16, zero-pad k>=300
#define WS_SH 0
#define WS_W  3200
#define WS_NR 6400
#define WS_S0 6500
#define WS_STAGE 6532       // floats staged to LDS (= 26128 B = 1633 float4)
#define WS_PA 6532

__device__ inline float fast_exp2(float x) {
#if __has_builtin(__builtin_amdgcn_exp2f)
    return __builtin_amdgcn_exp2f(x);
#else
    return exp2f(x);
#endif
}
__device__ inline float fast_rcp(float x) {
#if __has_builtin(__builtin_amdgcn_rcpf)
    return __builtin_amdgcn_rcpf(x);
#else
    return 1.0f / x;
#endif
}
__device__ inline ushort f2bf(float f) {        // RNE f32->bf16 (round-2-proven)
    uint u = __builtin_bit_cast(uint, f);
    u += 0x7fffu + ((u >> 16) & 1u);
    return (ushort)(u >> 16);
}
__device__ inline s16x8 pack_bf8(f32x4 lo, f32x4 hi) {   // round-2-proven path
    s16x8 bb;
    bb[0] = (short)f2bf(lo[0]); bb[1] = (short)f2bf(lo[1]);
    bb[2] = (short)f2bf(lo[2]); bb[3] = (short)f2bf(lo[3]);
    bb[4] = (short)f2bf(hi[0]); bb[5] = (short)f2bf(hi[1]);
    bb[6] = (short)f2bf(hi[2]); bb[7] = (short)f2bf(hi[3]);
    return bb;
}

__global__ __launch_bounds__(320) void prep_kernel(
    const int* __restrict__ e1, const int* __restrict__ rel,
    const float* __restrict__ emb_e, const float* __restrict__ emb_rel,
    const float* __restrict__ num_lit, const float* __restrict__ num_lit_norm,
    const float* __restrict__ W, const float* __restrict__ b_lit,
    const float* __restrict__ c, const float* __restrict__ var,
    const float* __restrict__ nf_w, float* __restrict__ ws)
{
    const int b = blockIdx.x;
    const int t = threadIdx.x;
    __shared__ float q[D_N];
    const int e1b = e1[b];
    const int rb  = rel[b];

    if (t < D_N) {
        const float* wr = W + t * K_N;
        const float* er = emb_e + (long)e1b * D_N;
        const float* nl = num_lit_norm + (long)e1b * L_N;
        float s0_ = b_lit[t], s1_ = 0.f, s2_ = 0.f, s3_ = 0.f;
        for (int k = 0; k < D_N; k += 4) {
            s0_ += er[k+0] * wr[k+0]; s1_ += er[k+1] * wr[k+1];
            s2_ += er[k+2] * wr[k+2]; s3_ += er[k+3] * wr[k+3];
        }
        for (int k = 0; k < L_N; k += 4) {
            s0_ += nl[k+0] * wr[D_N+k+0]; s1_ += nl[k+1] * wr[D_N+k+1];
            s2_ += nl[k+2] * wr[D_N+k+2]; s3_ += nl[k+3] * wr[D_N+k+3];
        }
        q[t] = ((s0_ + s1_) + (s2_ + s3_)) * emb_rel[rb * D_N + t];
    }
    __syncthreads();

    {   // p[b,k] = sum_d q[d]*W[d,k]  -> bf16, A-frag layout
        float pk = 0.f;
        if (t < K_N) {
            float a0 = 0.f, a1 = 0.f, a2 = 0.f, a3 = 0.f;
            for (int d = 0; d < D_N; d += 4) {
                a0 += q[d+0] * W[(d+0) * K_N + t];
                a1 += q[d+1] * W[(d+1) * K_N + t];
                a2 += q[d+2] * W[(d+2) * K_N + t];
                a3 += q[d+3] * W[(d+3) * K_N + t];
            }
            pk = (a0 + a1) + (a2 + a3);
        }
        const int s  = t >> 5;
        const int g  = (t >> 3) & 3;
        const int j  = t & 7;
        const int mt = b >> 4;
        const int ln = (g << 4) | (b & 15);
        ushort* pa = (ushort*)(ws + WS_PA);
        pa[((mt * 10 + s) * 64 + ln) * 8 + j] = f2bf(pk);
    }

    if (t < L_N) {
        const float r = sqrtf(1.4426950408889634f / var[t]);
        ws[WS_SH + t * 32 + b] = r * (num_lit[(long)e1b * L_N + t] - c[t]);
        ws[WS_W  + t * 32 + b] = nf_w[rb * L_N + t];
        if (b == 0) ws[WS_NR + t] = -r;
    }
    if (t == 300) {
        float s = 0.f;
        for (int d = 0; d < D_N; ++d) s += q[d] * b_lit[d];
        ws[WS_S0 + b] = s;
    }
}

__global__ __launch_bounds__(256, 6) void score_kernel(
    const float* __restrict__ emb_e, const float* __restrict__ num_lit,
    const float* __restrict__ num_lit_norm, const float* __restrict__ ws,
    float* __restrict__ out)
{
    __shared__ float smem[WS_STAGE];

    const int lane = threadIdx.x & 63;
    const int wv   = threadIdx.x >> 6;
    const int tile = blockIdx.x * 4 + wv;      // [0, 5000)
    const int mt   = tile & 1;                 // b-half
    const int eg   = tile >> 1;                // e-group
    const int er   = lane & 15;
    const int g    = lane >> 4;
    const int e    = eg * 16 + er;
    const int b0   = mt * 16 + 4 * g;

    // ---- stage RBF tables to LDS (26128 B = 1633 float4); barrier deferred
    //      until after the MFMA phase (which touches only global memory).
    {
        const f32x4* s4 = (const f32x4*)ws;
        f32x4* d4 = (f32x4*)smem;
        for (int i = threadIdx.x; i < 1633; i += 256) d4[i] = s4[i];
    }

    // ---- acc init straight from global (16B broadcast, L2-hot) ----
    f32x4 acc = *(const f32x4*)(ws + WS_S0 + b0);

    // ---- A fragments: global -> registers (coalesced 16B/lane, dead after MFMA)
    s16x8 afr[10];
    {
        const s16x8* pAg = (const s16x8*)(ws + WS_PA);
#pragma unroll
        for (int s = 0; s < 10; ++s) afr[s] = pAg[(mt * 10 + s) * 64 + lane];
    }

    const float* embr = emb_e        + (long)e * D_N;
    const float* litn = num_lit_norm + (long)e * L_N;

    // ---- score_l via MFMA: D[b,e] = sum_k p[b,k]*cat_e[k] ----
#pragma unroll
    for (int s = 0; s < 9; ++s) {
        const int k0 = 32 * s + 8 * g;
        const float* bp = (k0 < 200) ? (embr + k0) : (litn + (k0 - 200));
        f32x4 lo = *(const f32x4*)bp;
        f32x4 hi = *(const f32x4*)(bp + 4);
        acc = __builtin_amdgcn_mfma_f32_16x16x32_bf16(afr[s], pack_bf8(lo, hi), acc, 0, 0, 0);
    }
    {   // step 9: k = 288..319 (real lit 88..99; A is zero-padded for k>=300)
        f32x4 z = {0.f, 0.f, 0.f, 0.f};
        f32x4 lo = z, hi = z;
        if (g == 0)      { lo = *(const f32x4*)(litn + 88); hi = *(const f32x4*)(litn + 92); }
        else if (g == 1) { lo = *(const f32x4*)(litn + 96); }
        acc = __builtin_amdgcn_mfma_f32_16x16x32_bf16(afr[9], pack_bf8(lo, hi), acc, 0, 0, 0);
    }

    __syncthreads();    // LDS tables now needed

    const float* shL = smem + WS_SH;
    const float* wL  = smem + WS_W;
    const float* nrL = smem + WS_NR;

    // ---- score_n: RBF over 100 literals, mrow prefetched 2 groups ahead ----
    const f32x4* m4 = (const f32x4*)(num_lit + (long)e * L_N);   // 25 groups
    const f32x4* n4 = (const f32x4*)nrL;
    f32x4 mv_a = m4[0];
    f32x4 mv_b = m4[1];
#pragma unroll 5
    for (int lc = 0; lc < 25; ++lc) {
        const f32x4 mv = mv_a;
        mv_a = mv_b;
        if (lc + 2 < 25) mv_b = m4[lc + 2];
        f32x4 nv = n4[lc];
#pragma unroll
        for (int ll = 0; ll < 4; ++ll) {
            const int l = lc * 4 + ll;
            const float rm = nv[ll] * mv[ll];
            f32x4 s4 = *(const f32x4*)(shL + l * 32 + b0);
            f32x4 w4 = *(const f32x4*)(wL  + l * 32 + b0);
#pragma unroll
            for (int j = 0; j < 4; ++j) {
                const float u = rm + s4[j];
                acc[j] = fmaf(fast_exp2(-(u * u)), w4[j], acc[j]);
            }
        }
    }

    // ---- sigmoid + store ----
#pragma unroll
    for (int j = 0; j < 4; ++j) {
        const float z = fast_exp2(acc[j] * -1.4426950408889634f);
        out[(long)(b0 + j) * E_N + e] = fast_rcp(1.0f + z);
    }
}

extern "C" void kernel_launch(void* const* d_in, const int* in_sizes, int n_in,
                              void* d_out, int out_size, void* d_ws, size_t ws_size,
                              hipStream_t stream) {
    const int*   e1       = (const int*)d_in[0];
    const int*   rel      = (const int*)d_in[1];
    const float* emb_e    = (const float*)d_in[2];
    const float* emb_rel  = (const float*)d_in[3];
    const float* num_lit  = (const float*)d_in[4];
    const float* num_lit_norm = (const float*)d_in[5];
    const float* W_lit    = (const float*)d_in[6];
    const float* b_lit    = (const float*)d_in[7];
    const float* c        = (const float*)d_in[8];
    const float* var      = (const float*)d_in[9];
    const float* nf_w     = (const float*)d_in[10];
    float* out = (float*)d_out;
    float* ws  = (float*)d_ws;

    hipLaunchKernelGGL(prep_kernel, dim3(B_N), dim3(320), 0, stream,
                       e1, rel, emb_e, emb_rel, num_lit, num_lit_norm,
                       W_lit, b_lit, c, var, nf_w, ws);
    hipLaunchKernelGGL(score_kernel, dim3(1250), dim3(256), 0, stream,
                       emb_e, num_lit, num_lit_norm, ws, out);
}

// Round 6
// 47.986 us; speedup vs baseline: 5.1130x; 5.1130x over previous
//
#include <hip/hip_runtime.h>
#include <math.h>

#define E_N 40000
#define D_N 200
#define L_N 100
#define K_N 300
#define B_N 32

typedef float  f32x4 __attribute__((ext_vector_type(4)));
typedef short  s16x8 __attribute__((ext_vector_type(8)));

// ws layout (f32 units):
//  sh  [100][32] @ 0      r_l*(num_lit[e1_b,l]-c_l)
//  w   [100][32] @ 3200   nf_w[rel_b,l]
//  nr  [100]     @ 6400   -r_l,  r_l = sqrt(log2e/var_l)
//  s0  [32]      @ 6500   q[b,:].b_lit   (pad to 6532)
//  pA  u16[2][10][64][8] @ 6532   p in MFMA A-frag layout, bf16, zero-pad k>=300
#define WS_SH 0
#define WS_W  3200
#define WS_NR 6400
#define WS_S0 6500
#define WS_STAGE 6532       // floats staged to LDS (= 26128 B = 1633 float4)
#define WS_PA 6532

__device__ inline float fast_exp2(float x) {
#if __has_builtin(__builtin_amdgcn_exp2f)
    return __builtin_amdgcn_exp2f(x);
#else
    return exp2f(x);
#endif
}
__device__ inline float fast_rcp(float x) {
#if __has_builtin(__builtin_amdgcn_rcpf)
    return __builtin_amdgcn_rcpf(x);
#else
    return 1.0f / x;
#endif
}
__device__ inline ushort f2bf(float f) {        // RNE f32->bf16 (round-2-proven)
    uint u = __builtin_bit_cast(uint, f);
    u += 0x7fffu + ((u >> 16) & 1u);
    return (ushort)(u >> 16);
}
__device__ inline s16x8 pack_bf8(f32x4 lo, f32x4 hi) {   // round-2-proven path
    s16x8 bb;
    bb[0] = (short)f2bf(lo[0]); bb[1] = (short)f2bf(lo[1]);
    bb[2] = (short)f2bf(lo[2]); bb[3] = (short)f2bf(lo[3]);
    bb[4] = (short)f2bf(hi[0]); bb[5] = (short)f2bf(hi[1]);
    bb[6] = (short)f2bf(hi[2]); bb[7] = (short)f2bf(hi[3]);
    return bb;
}

__global__ __launch_bounds__(320) void prep_kernel(
    const int* __restrict__ e1, const int* __restrict__ rel,
    const float* __restrict__ emb_e, const float* __restrict__ emb_rel,
    const float* __restrict__ num_lit, const float* __restrict__ num_lit_norm,
    const float* __restrict__ W, const float* __restrict__ b_lit,
    const float* __restrict__ c, const float* __restrict__ var,
    const float* __restrict__ nf_w, float* __restrict__ ws)
{
    const int b = blockIdx.x;
    const int t = threadIdx.x;
    __shared__ float q[D_N];
    const int e1b = e1[b];
    const int rb  = rel[b];

    if (t < D_N) {
        const float* wr = W + t * K_N;
        const float* er = emb_e + (long)e1b * D_N;
        const float* nl = num_lit_norm + (long)e1b * L_N;
        float s0_ = b_lit[t], s1_ = 0.f, s2_ = 0.f, s3_ = 0.f;
        for (int k = 0; k < D_N; k += 4) {
            s0_ += er[k+0] * wr[k+0]; s1_ += er[k+1] * wr[k+1];
            s2_ += er[k+2] * wr[k+2]; s3_ += er[k+3] * wr[k+3];
        }
        for (int k = 0; k < L_N; k += 4) {
            s0_ += nl[k+0] * wr[D_N+k+0]; s1_ += nl[k+1] * wr[D_N+k+1];
            s2_ += nl[k+2] * wr[D_N+k+2]; s3_ += nl[k+3] * wr[D_N+k+3];
        }
        q[t] = ((s0_ + s1_) + (s2_ + s3_)) * emb_rel[rb * D_N + t];
    }
    __syncthreads();

    {   // p[b,k] = sum_d q[d]*W[d,k]  -> bf16, A-frag layout
        float pk = 0.f;
        if (t < K_N) {
            float a0 = 0.f, a1 = 0.f, a2 = 0.f, a3 = 0.f;
            for (int d = 0; d < D_N; d += 4) {
                a0 += q[d+0] * W[(d+0) * K_N + t];
                a1 += q[d+1] * W[(d+1) * K_N + t];
                a2 += q[d+2] * W[(d+2) * K_N + t];
                a3 += q[d+3] * W[(d+3) * K_N + t];
            }
            pk = (a0 + a1) + (a2 + a3);
        }
        const int s  = t >> 5;
        const int g  = (t >> 3) & 3;
        const int j  = t & 7;
        const int mt = b >> 4;
        const int ln = (g << 4) | (b & 15);
        ushort* pa = (ushort*)(ws + WS_PA);
        pa[((mt * 10 + s) * 64 + ln) * 8 + j] = f2bf(pk);
    }

    if (t < L_N) {
        const float r = sqrtf(1.4426950408889634f / var[t]);
        ws[WS_SH + t * 32 + b] = r * (num_lit[(long)e1b * L_N + t] - c[t]);
        ws[WS_W  + t * 32 + b] = nf_w[rb * L_N + t];
        if (b == 0) ws[WS_NR + t] = -r;
    }
    if (t == 300) {
        float s = 0.f;
        for (int d = 0; d < D_N; ++d) s += q[d] * b_lit[d];
        ws[WS_S0 + b] = s;
    }
}

__global__ __launch_bounds__(256, 4) void score_kernel(
    const float* __restrict__ emb_e, const float* __restrict__ num_lit,
    const float* __restrict__ num_lit_norm, const float* __restrict__ ws,
    float* __restrict__ out)
{
    __shared__ float smem[WS_STAGE];

    const int lane = threadIdx.x & 63;
    const int wv   = threadIdx.x >> 6;
    const int tile = blockIdx.x * 4 + wv;      // [0, 5000)
    const int mt   = tile & 1;                 // b-half
    const int eg   = tile >> 1;                // e-group
    const int er   = lane & 15;
    const int g    = lane >> 4;
    const int e    = eg * 16 + er;
    const int b0   = mt * 16 + 4 * g;

    // ---- stage RBF tables to LDS (26128 B = 1633 float4); barrier deferred
    //      until after the MFMA phase (which touches only global memory).
    {
        const f32x4* s4 = (const f32x4*)ws;
        f32x4* d4 = (f32x4*)smem;
        for (int i = threadIdx.x; i < 1633; i += 256) d4[i] = s4[i];
    }

    // ---- acc init straight from global (16B broadcast, L2-hot) ----
    f32x4 acc = *(const f32x4*)(ws + WS_S0 + b0);

    // ---- A fragments: global -> registers (coalesced 16B/lane, dead after MFMA)
    s16x8 afr[10];
    {
        const s16x8* pAg = (const s16x8*)(ws + WS_PA);
#pragma unroll
        for (int s = 0; s < 10; ++s) afr[s] = pAg[(mt * 10 + s) * 64 + lane];
    }

    const float* embr = emb_e        + (long)e * D_N;
    const float* litn = num_lit_norm + (long)e * L_N;

    // ---- score_l via MFMA: D[b,e] = sum_k p[b,k]*cat_e[k] ----
#pragma unroll
    for (int s = 0; s < 9; ++s) {
        const int k0 = 32 * s + 8 * g;
        const float* bp = (k0 < 200) ? (embr + k0) : (litn + (k0 - 200));
        f32x4 lo = *(const f32x4*)bp;
        f32x4 hi = *(const f32x4*)(bp + 4);
        acc = __builtin_amdgcn_mfma_f32_16x16x32_bf16(afr[s], pack_bf8(lo, hi), acc, 0, 0, 0);
    }
    {   // step 9: k = 288..319 (real lit 88..99; A is zero-padded for k>=300)
        f32x4 z = {0.f, 0.f, 0.f, 0.f};
        f32x4 lo = z, hi = z;
        if (g == 0)      { lo = *(const f32x4*)(litn + 88); hi = *(const f32x4*)(litn + 92); }
        else if (g == 1) { lo = *(const f32x4*)(litn + 96); }
        acc = __builtin_amdgcn_mfma_f32_16x16x32_bf16(afr[9], pack_bf8(lo, hi), acc, 0, 0, 0);
    }

    __syncthreads();    // LDS tables now needed

    const float* shL = smem + WS_SH;
    const float* wL  = smem + WS_W;
    const float* nrL = smem + WS_NR;

    // ---- score_n: RBF over 100 literals; 2-deep mrow prefetch, natural loop ----
    const f32x4* m4 = (const f32x4*)(num_lit + (long)e * L_N);   // 25 groups
    const f32x4* n4 = (const f32x4*)nrL;
    f32x4 mv_a = m4[0];
    f32x4 mv_b = m4[1];
    for (int lc = 0; lc < 25; ++lc) {
        const f32x4 mv = mv_a;
        mv_a = mv_b;
        if (lc + 2 < 25) mv_b = m4[lc + 2];
        f32x4 nv = n4[lc];
#pragma unroll
        for (int ll = 0; ll < 4; ++ll) {
            const int l = lc * 4 + ll;
            const float rm = nv[ll] * mv[ll];
            f32x4 s4 = *(const f32x4*)(shL + l * 32 + b0);
            f32x4 w4 = *(const f32x4*)(wL  + l * 32 + b0);
#pragma unroll
            for (int j = 0; j < 4; ++j) {
                const float u = rm + s4[j];
                acc[j] = fmaf(fast_exp2(-(u * u)), w4[j], acc[j]);
            }
        }
    }

    // ---- sigmoid + store ----
#pragma unroll
    for (int j = 0; j < 4; ++j) {
        const float z = fast_exp2(acc[j] * -1.4426950408889634f);
        out[(long)(b0 + j) * E_N + e] = fast_rcp(1.0f + z);
    }
}

extern "C" void kernel_launch(void* const* d_in, const int* in_sizes, int n_in,
                              void* d_out, int out_size, void* d_ws, size_t ws_size,
                              hipStream_t stream) {
    const int*   e1       = (const int*)d_in[0];
    const int*   rel      = (const int*)d_in[1];
    const float* emb_e    = (const float*)d_in[2];
    const float* emb_rel  = (const float*)d_in[3];
    const float* num_lit  = (const float*)d_in[4];
    const float* num_lit_norm = (const float*)d_in[5];
    const float* W_lit    = (const float*)d_in[6];
    const float* b_lit    = (const float*)d_in[7];
    const float* c        = (const float*)d_in[8];
    const float* var      = (const float*)d_in[9];
    const float* nf_w     = (const float*)d_in[10];
    float* out = (float*)d_out;
    float* ws  = (float*)d_ws;

    hipLaunchKernelGGL(prep_kernel, dim3(B_N), dim3(320), 0, stream,
                       e1, rel, emb_e, emb_rel, num_lit, num_lit_norm,
                       W_lit, b_lit, c, var, nf_w, ws);
    hipLaunchKernelGGL(score_kernel, dim3(1250), dim3(256), 0, stream,
                       emb_e, num_lit, num_lit_norm, ws, out);
}